// Round 1
// baseline (1353.492 us; speedup 1.0000x reference)
//
#include <hip/hip_runtime.h>

// Problem constants
static constexpr int kN = 50000;      // nodes per side
static constexpr int kE = 800000;     // edges per side
static constexpr int kG = 1024;       // graphs
static constexpr int kEMB = 128;
static constexpr int kGH = 256;
static constexpr int kEH = 256;
static constexpr int kOUT = 128;
static constexpr int kHID = 512;

// ---------------------------------------------------------------------------
// Graph structure kernels (CSR build via counting sort)
// ---------------------------------------------------------------------------

__global__ void deg_kernel(const int* __restrict__ dst, int* __restrict__ counts, int e_count) {
    int i = blockIdx.x * blockDim.x + threadIdx.x;
    if (i < e_count) atomicAdd(&counts[dst[i]], 1);
}

// Single-block prefix scan: row_ptr[0]=0, row_ptr[i+1]=sum(counts[0..i])
__launch_bounds__(1024)
__global__ void scan_kernel(const int* __restrict__ counts, int* __restrict__ row_ptr, int n) {
    __shared__ int sdata[1024];
    __shared__ int base_s;
    int tid = threadIdx.x;
    if (tid == 0) { base_s = 0; row_ptr[0] = 0; }
    __syncthreads();
    for (int start = 0; start < n; start += 1024) {
        int i = start + tid;
        int v = (i < n) ? counts[i] : 0;
        sdata[tid] = v;
        __syncthreads();
        // Hillis-Steele inclusive scan
        for (int off = 1; off < 1024; off <<= 1) {
            int t = (tid >= off) ? sdata[tid - off] : 0;
            __syncthreads();
            sdata[tid] += t;
            __syncthreads();
        }
        if (i < n) row_ptr[i + 1] = base_s + sdata[tid];
        __syncthreads();
        if (tid == 0) base_s += sdata[1023];
        __syncthreads();
    }
}

__global__ void dinv_kernel(const int* __restrict__ counts, float* __restrict__ dinv, int n) {
    int i = blockIdx.x * blockDim.x + threadIdx.x;
    if (i < n) dinv[i] = rsqrtf((float)(counts[i] + 1));   // +1 self-loop
}

__global__ void fill_kernel(const int* __restrict__ src, const int* __restrict__ dst,
                            const int* __restrict__ row_ptr, int* __restrict__ fillc,
                            int* __restrict__ col_idx, int e_count) {
    int i = blockIdx.x * blockDim.x + threadIdx.x;
    if (i < e_count) {
        int d = dst[i];
        int pos = row_ptr[d] + atomicAdd(&fillc[d], 1);
        col_idx[pos] = src[i];
    }
}

// ---------------------------------------------------------------------------
// M11 = atom_emb @ gW1  [11,256] -- conv1's GEMM collapses to this tiny table
// ---------------------------------------------------------------------------
__global__ void m11_kernel(const float* __restrict__ atom_emb, const float* __restrict__ gW1,
                           float* __restrict__ M11) {
    int c = threadIdx.x;  // 256 channels
    for (int r = 0; r < 11; r++) {
        float s = 0.f;
        for (int k = 0; k < kEMB; k++) s += atom_emb[r * kEMB + k] * gW1[k * kGH + c];
        M11[r * kGH + c] = s;
    }
}

// ---------------------------------------------------------------------------
// Conv1 fused: h2[v] = relu(dinv[v]*(dinv[v]*M11[x[v]] + sum_s dinv[s]*M11[x[s]]) + b1)
// One wave per node, lane handles 4 channels (float4). M11 is 11KB -> L1 resident.
// ---------------------------------------------------------------------------
__global__ void aggregate1_kernel(const int* __restrict__ x, const float* __restrict__ dinv,
                                  const int* __restrict__ row_ptr, const int* __restrict__ col_idx,
                                  const float* __restrict__ M11, const float* __restrict__ bias,
                                  float* __restrict__ out, int n) {
    int wave = threadIdx.x >> 6;
    int lane = threadIdx.x & 63;
    int v = blockIdx.x * 4 + wave;
    if (v >= n) return;
    int c = lane * 4;
    float4 bia = *(const float4*)(bias + c);
    float dv = dinv[v];
    int xv = x[v];
    float4 m = *(const float4*)(M11 + xv * kGH + c);
    float4 acc = make_float4(dv * m.x, dv * m.y, dv * m.z, dv * m.w);
    int e0 = row_ptr[v], e1 = row_ptr[v + 1];
    for (int e = e0; e < e1; e++) {
        int s = col_idx[e];
        float ds = dinv[s];
        int xs = x[s];
        float4 ms = *(const float4*)(M11 + xs * kGH + c);
        acc.x += ds * ms.x; acc.y += ds * ms.y; acc.z += ds * ms.z; acc.w += ds * ms.w;
    }
    float4 o;
    o.x = fmaxf(dv * acc.x + bia.x, 0.f);
    o.y = fmaxf(dv * acc.y + bia.y, 0.f);
    o.z = fmaxf(dv * acc.z + bia.z, 0.f);
    o.w = fmaxf(dv * acc.w + bia.w, 0.f);
    *(float4*)(out + (size_t)v * kGH + c) = o;
}

// ---------------------------------------------------------------------------
// Conv2 aggregate: h4[v] = relu(dinv[v]*(hs[v] + sum_s hs[s]) + b2), hs already dinv-scaled
// ---------------------------------------------------------------------------
__global__ void aggregate2_kernel(const float* __restrict__ hs, const float* __restrict__ dinv,
                                  const int* __restrict__ row_ptr, const int* __restrict__ col_idx,
                                  const float* __restrict__ bias, float* __restrict__ out, int n) {
    int wave = threadIdx.x >> 6;
    int lane = threadIdx.x & 63;
    int v = blockIdx.x * 4 + wave;
    if (v >= n) return;
    int c = lane * 4;
    float4 bia = *(const float4*)(bias + c);
    float dv = dinv[v];
    float4 acc = *(const float4*)(hs + (size_t)v * kGH + c);  // self-loop term
    int e0 = row_ptr[v], e1 = row_ptr[v + 1];
    for (int e = e0; e < e1; e++) {
        int s = col_idx[e];
        float4 hv = *(const float4*)(hs + (size_t)s * kGH + c);
        acc.x += hv.x; acc.y += hv.y; acc.z += hv.z; acc.w += hv.w;
    }
    float4 o;
    o.x = fmaxf(dv * acc.x + bia.x, 0.f);
    o.y = fmaxf(dv * acc.y + bia.y, 0.f);
    o.z = fmaxf(dv * acc.z + bia.z, 0.f);
    o.w = fmaxf(dv * acc.w + bia.w, 0.f);
    *(float4*)(out + (size_t)v * kGH + c) = o;
}

// ---------------------------------------------------------------------------
// Global mean pool: batch is sorted -> binary search boundaries, atomic-free
// ---------------------------------------------------------------------------
__global__ void pool_kernel(const float* __restrict__ h, const int* __restrict__ batch,
                            float* __restrict__ pooled, int n) {
    int g = blockIdx.x;
    int lo = 0, hi = n;
    while (lo < hi) { int mid = (lo + hi) >> 1; if (batch[mid] < g) lo = mid + 1; else hi = mid; }
    int start = lo;
    lo = start; hi = n;
    while (lo < hi) { int mid = (lo + hi) >> 1; if (batch[mid] < g + 1) lo = mid + 1; else hi = mid; }
    int end = lo;
    int c = threadIdx.x;  // 256
    float s = 0.f;
    for (int v = start; v < end; v++) s += h[(size_t)v * kGH + c];
    float cnt = (float)(end - start);
    pooled[g * kGH + c] = s / fmaxf(cnt, 1.0f);
}

// ---------------------------------------------------------------------------
// Entity embedding gather + relu
// ---------------------------------------------------------------------------
__global__ void ent_gather_kernel(const float* __restrict__ emb, const int* __restrict__ ent,
                                  float* __restrict__ out) {
    int i = blockIdx.x * blockDim.x + threadIdx.x;
    if (i >= kG * kEMB) return;
    int g = i >> 7, c = i & 127;
    out[i] = fmaxf(emb[(size_t)ent[g] * kEMB + c], 0.f);
}

// ---------------------------------------------------------------------------
// egs = relu(concat(g1,e1) + concat(g2,e2))  [G,512]
// ---------------------------------------------------------------------------
__global__ void egs_kernel(const float* __restrict__ g1, const float* __restrict__ g2,
                           const float* __restrict__ e1, const float* __restrict__ e2,
                           float* __restrict__ egs) {
    int i = blockIdx.x * blockDim.x + threadIdx.x;
    if (i >= kG * kHID) return;
    int g = i >> 9, c = i & 511;
    float v;
    if (c < kGH) v = g1[g * kGH + c] + g2[g * kGH + c];
    else         v = e1[g * kEH + c - kGH] + e2[g * kEH + c - kGH];
    egs[i] = fmaxf(v, 0.f);
}

// ---------------------------------------------------------------------------
// Generic tiled fp32 GEMM: C = op(row_scale ? rs[m]*(A@B) : A@B [+ bias] [relu])
// BM=BN=64, BK=16, 256 threads, 4x4 microtile. Requires K%16==0, N%64==0.
// ---------------------------------------------------------------------------
__launch_bounds__(256)
__global__ void gemm_kernel(const float* __restrict__ A, const float* __restrict__ B,
                            float* __restrict__ C, int M, int N, int K,
                            const float* __restrict__ bias,
                            const float* __restrict__ row_scale, int relu) {
    __shared__ float As[16][64];
    __shared__ float Bs[16][64];
    int tid = threadIdx.x;
    int tx = tid & 15, ty = tid >> 4;
    int row0 = blockIdx.y * 64, col0 = blockIdx.x * 64;
    float acc[4][4] = {};
    for (int k0 = 0; k0 < K; k0 += 16) {
        {   // A tile 64x16, transposed into LDS
            int r = tid >> 2, seg = tid & 3;
            int gr = row0 + r;
            float4 v = make_float4(0.f, 0.f, 0.f, 0.f);
            if (gr < M) v = *(const float4*)(A + (size_t)gr * K + k0 + seg * 4);
            As[seg * 4 + 0][r] = v.x; As[seg * 4 + 1][r] = v.y;
            As[seg * 4 + 2][r] = v.z; As[seg * 4 + 3][r] = v.w;
        }
        {   // B tile 16x64
            int kr = tid >> 4, c4 = (tid & 15) * 4;
            float4 v = *(const float4*)(B + (size_t)(k0 + kr) * N + col0 + c4);
            *(float4*)&Bs[kr][c4] = v;
        }
        __syncthreads();
        #pragma unroll
        for (int k = 0; k < 16; k++) {
            float a[4], b[4];
            #pragma unroll
            for (int i = 0; i < 4; i++) a[i] = As[k][ty * 4 + i];
            #pragma unroll
            for (int j = 0; j < 4; j++) b[j] = Bs[k][tx * 4 + j];
            #pragma unroll
            for (int i = 0; i < 4; i++)
                #pragma unroll
                for (int j = 0; j < 4; j++)
                    acc[i][j] += a[i] * b[j];
        }
        __syncthreads();
    }
    #pragma unroll
    for (int i = 0; i < 4; i++) {
        int gr = row0 + ty * 4 + i;
        if (gr >= M) continue;
        float rs = row_scale ? row_scale[gr] : 1.0f;
        #pragma unroll
        for (int j = 0; j < 4; j++) {
            int gc = col0 + tx * 4 + j;
            float v = acc[i][j] * rs;
            if (bias) v += bias[gc];
            if (relu) v = fmaxf(v, 0.f);
            C[(size_t)gr * N + gc] = v;
        }
    }
}

// ---------------------------------------------------------------------------
// Host launch
// ---------------------------------------------------------------------------
static inline char* carve(char*& p, size_t bytes) {
    char* r = p;
    p += (bytes + 255) & ~(size_t)255;
    return r;
}

extern "C" void kernel_launch(void* const* d_in, const int* in_sizes, int n_in,
                              void* d_out, int out_size, void* d_ws, size_t ws_size,
                              hipStream_t stream) {
    const int*   x1       = (const int*)d_in[0];
    const int*   ei1      = (const int*)d_in[1];
    const int*   ent1     = (const int*)d_in[2];
    const int*   batch1   = (const int*)d_in[3];
    const int*   x2       = (const int*)d_in[4];
    const int*   ei2      = (const int*)d_in[5];
    const int*   ent2     = (const int*)d_in[6];
    const int*   batch2   = (const int*)d_in[7];
    const float* atom_emb = (const float*)d_in[8];
    const float* gW1      = (const float*)d_in[9];
    const float* gb1      = (const float*)d_in[10];
    const float* gW2      = (const float*)d_in[11];
    const float* gb2      = (const float*)d_in[12];
    const float* fcW      = (const float*)d_in[13];
    const float* fcb      = (const float*)d_in[14];
    const float* ent_emb  = (const float*)d_in[15];
    const float* eW1      = (const float*)d_in[16];
    const float* eb1      = (const float*)d_in[17];
    const float* eW2      = (const float*)d_in[18];
    const float* eb2      = (const float*)d_in[19];
    const float* dW1      = (const float*)d_in[20];
    const float* db1      = (const float*)d_in[21];
    const float* dW2      = (const float*)d_in[22];
    const float* db2      = (const float*)d_in[23];
    const float* dW3      = (const float*)d_in[24];
    const float* db3      = (const float*)d_in[25];
    float* out = (float*)d_out;

    // Workspace carve
    char* p = (char*)d_ws;
    float* bufA    = (float*)carve(p, (size_t)kN * kGH * 4);
    float* bufB    = (float*)carve(p, (size_t)kN * kGH * 4);
    int*   col_idx = (int*)  carve(p, (size_t)kE * 4);
    int*   row_ptr = (int*)  carve(p, (size_t)(kN + 1) * 4);
    int*   counts  = (int*)  carve(p, (size_t)kN * 4);
    int*   fillc   = (int*)  carve(p, (size_t)kN * 4);
    float* dinv    = (float*)carve(p, (size_t)kN * 4);
    float* M11     = (float*)carve(p, 11 * kGH * 4);
    float* pooled1 = (float*)carve(p, (size_t)kG * kGH * 4);
    float* pooled2 = (float*)carve(p, (size_t)kG * kGH * 4);
    float* g1      = (float*)carve(p, (size_t)kG * kGH * 4);
    float* g2      = (float*)carve(p, (size_t)kG * kGH * 4);
    float* e0      = (float*)carve(p, (size_t)kG * kEMB * 4);
    float* etmp    = (float*)carve(p, (size_t)kG * kEH * 4);
    float* ent1o   = (float*)carve(p, (size_t)kG * kEH * 4);
    float* ent2o   = (float*)carve(p, (size_t)kG * kEH * 4);
    float* egs     = (float*)carve(p, (size_t)kG * kHID * 4);
    float* dh1     = (float*)carve(p, (size_t)kG * kHID * 4);
    float* dh2     = (float*)carve(p, (size_t)kG * kHID * 4);

    // M11 = atom_emb @ gW1 (conv1 GEMM collapsed to an 11-row table)
    m11_kernel<<<1, 256, 0, stream>>>(atom_emb, gW1, M11);

    const int* xs[2]      = {x1, x2};
    const int* eis[2]     = {ei1, ei2};
    const int* batches[2] = {batch1, batch2};
    float* pooleds[2]     = {pooled1, pooled2};

    for (int b = 0; b < 2; b++) {
        const int* src = eis[b];
        const int* dst = eis[b] + kE;
        hipMemsetAsync(counts, 0, (size_t)kN * 4, stream);
        hipMemsetAsync(fillc, 0, (size_t)kN * 4, stream);
        deg_kernel<<<(kE + 255) / 256, 256, 0, stream>>>(dst, counts, kE);
        scan_kernel<<<1, 1024, 0, stream>>>(counts, row_ptr, kN);
        dinv_kernel<<<(kN + 255) / 256, 256, 0, stream>>>(counts, dinv, kN);
        fill_kernel<<<(kE + 255) / 256, 256, 0, stream>>>(src, dst, row_ptr, fillc, col_idx, kE);
        // conv1 fully fused (embed gather + GEMM via M11 + aggregate + bias + relu)
        aggregate1_kernel<<<(kN + 3) / 4, 256, 0, stream>>>(xs[b], dinv, row_ptr, col_idx,
                                                            M11, gb1, bufA, kN);
        // conv2 GEMM: hs2 = dinv ⊙ (h2 @ gW2)
        {
            dim3 grid(kGH / 64, (kN + 63) / 64);
            gemm_kernel<<<grid, 256, 0, stream>>>(bufA, gW2, bufB, kN, kGH, kGH,
                                                  nullptr, dinv, 0);
        }
        aggregate2_kernel<<<(kN + 3) / 4, 256, 0, stream>>>(bufB, dinv, row_ptr, col_idx,
                                                            gb2, bufA, kN);
        pool_kernel<<<kG, 256, 0, stream>>>(bufA, batches[b], pooleds[b], kN);
    }

    // fc on pooled (no relu)
    {
        dim3 grid(kGH / 64, kG / 64);
        gemm_kernel<<<grid, 256, 0, stream>>>(pooled1, fcW, g1, kG, kGH, kGH, fcb, nullptr, 0);
        gemm_kernel<<<grid, 256, 0, stream>>>(pooled2, fcW, g2, kG, kGH, kGH, fcb, nullptr, 0);
    }

    // entity encoders
    const int* ents[2] = {ent1, ent2};
    float* entouts[2]  = {ent1o, ent2o};
    for (int b = 0; b < 2; b++) {
        ent_gather_kernel<<<(kG * kEMB + 255) / 256, 256, 0, stream>>>(ent_emb, ents[b], e0);
        dim3 grid(kEH / 64, kG / 64);
        gemm_kernel<<<grid, 256, 0, stream>>>(e0, eW1, etmp, kG, kEH, kEMB, eb1, nullptr, 1);
        gemm_kernel<<<grid, 256, 0, stream>>>(etmp, eW2, entouts[b], kG, kEH, kEH, eb2, nullptr, 1);
    }

    // decoder
    egs_kernel<<<(kG * kHID + 255) / 256, 256, 0, stream>>>(g1, g2, ent1o, ent2o, egs);
    {
        dim3 grid(kHID / 64, kG / 64);
        gemm_kernel<<<grid, 256, 0, stream>>>(egs, dW1, dh1, kG, kHID, kHID, db1, nullptr, 1);
        gemm_kernel<<<grid, 256, 0, stream>>>(dh1, dW2, dh2, kG, kHID, kHID, db2, nullptr, 1);
    }
    {
        dim3 grid(kOUT / 64, kG / 64);
        gemm_kernel<<<grid, 256, 0, stream>>>(dh2, dW3, out, kG, kOUT, kHID, db3, nullptr, 0);
    }
}

// Round 2
// 942.369 us; speedup vs baseline: 1.4363x; 1.4363x over previous
//
#include <hip/hip_runtime.h>
#include <hip/hip_fp16.h>

// Problem constants
static constexpr int kN = 50000;      // nodes per side
static constexpr int kE = 800000;     // edges per side
static constexpr int kG = 1024;      // graphs
static constexpr int kEMB = 128;
static constexpr int kGH = 256;
static constexpr int kEH = 256;
static constexpr int kOUT = 128;
static constexpr int kHID = 512;
static constexpr int kNB = (kN + 255) / 256;   // 196 scan chunks per side

typedef __attribute__((ext_vector_type(8))) _Float16 half8v;
typedef __attribute__((ext_vector_type(4))) _Float16 half4v;
typedef __attribute__((ext_vector_type(4))) float floatx4;

// ---------------------------------------------------------------------------
// Graph structure: degree count (both sides via blockIdx.y)
// ---------------------------------------------------------------------------
__global__ void deg_kernel(const int* __restrict__ dst1, const int* __restrict__ dst2,
                           int* __restrict__ counts) {
    int side = blockIdx.y;
    const int* dst = side ? dst2 : dst1;
    int* c = counts + side * kN;
    int i = blockIdx.x * blockDim.x + threadIdx.x;
    if (i < kE) atomicAdd(&c[dst[i]], 1);
}

// Per-chunk sums (196 chunks per side)
__global__ void bsum_kernel(const int* __restrict__ counts, int* __restrict__ bsum) {
    int side = blockIdx.y;
    const int* c = counts + side * kN;
    int i = blockIdx.x * 256 + threadIdx.x;
    int v = (i < kN) ? c[i] : 0;
    #pragma unroll
    for (int o = 32; o; o >>= 1) v += __shfl_down(v, o);
    __shared__ int ws[4];
    if ((threadIdx.x & 63) == 0) ws[threadIdx.x >> 6] = v;
    __syncthreads();
    if (threadIdx.x == 0) bsum[side * kNB + blockIdx.x] = ws[0] + ws[1] + ws[2] + ws[3];
}

// Exclusive scan of the 196 chunk sums (one block per side)
__global__ void bscan_kernel(const int* __restrict__ bsum, int* __restrict__ boff) {
    int side = blockIdx.x;
    __shared__ int s[256];
    int t = threadIdx.x;
    int v = (t < kNB) ? bsum[side * kNB + t] : 0;
    s[t] = v;
    __syncthreads();
    for (int o = 1; o < 256; o <<= 1) {
        int u = (t >= o) ? s[t - o] : 0;
        __syncthreads();
        s[t] += u;
        __syncthreads();
    }
    if (t < kNB) boff[side * kNB + t] = s[t] - v;   // exclusive
}

// Final: local inclusive scan per chunk + chunk offset -> row_ptr
__global__ void scanf_kernel(const int* __restrict__ counts, const int* __restrict__ boff,
                             int* __restrict__ row_ptr) {
    int side = blockIdx.y;
    const int* c = counts + side * kN;
    int* rp = row_ptr + side * (kN + 1);
    int t = threadIdx.x;
    int i = blockIdx.x * 256 + t;
    __shared__ int s[256];
    int v = (i < kN) ? c[i] : 0;
    s[t] = v;
    __syncthreads();
    for (int o = 1; o < 256; o <<= 1) {
        int u = (t >= o) ? s[t - o] : 0;
        __syncthreads();
        s[t] += u;
        __syncthreads();
    }
    if (i < kN) rp[i + 1] = boff[side * kNB + blockIdx.x] + s[t];
    if (i == 0) rp[0] = 0;
}

__global__ void dinv_kernel(const int* __restrict__ counts, float* __restrict__ dinv) {
    int side = blockIdx.y;
    int i = blockIdx.x * blockDim.x + threadIdx.x;
    if (i < kN) dinv[side * kN + i] = rsqrtf((float)(counts[side * kN + i] + 1));  // +1 self-loop
}

__global__ void fill_kernel(const int* __restrict__ ei1, const int* __restrict__ ei2,
                            const int* __restrict__ row_ptr, int* __restrict__ fillc,
                            int* __restrict__ col_idx) {
    int side = blockIdx.y;
    const int* ei = side ? ei2 : ei1;
    const int* src = ei;
    const int* dst = ei + kE;
    const int* rp = row_ptr + side * (kN + 1);
    int* fc = fillc + side * kN;
    int* ci = col_idx + (size_t)side * kE;
    int i = blockIdx.x * blockDim.x + threadIdx.x;
    if (i < kE) {
        int d = dst[i];
        int pos = rp[d] + atomicAdd(&fc[d], 1);
        ci[pos] = src[i];
    }
}

// ---------------------------------------------------------------------------
// M11 = atom_emb @ gW1  [11,256];  W2T fp16 transpose  [n][k]
// ---------------------------------------------------------------------------
__global__ void m11_kernel(const float* __restrict__ atom_emb, const float* __restrict__ gW1,
                           float* __restrict__ M11) {
    int c = threadIdx.x;  // 256 channels
    for (int r = 0; r < 11; r++) {
        float s = 0.f;
        for (int k = 0; k < kEMB; k++) s += atom_emb[r * kEMB + k] * gW1[k * kGH + c];
        M11[r * kGH + c] = s;
    }
}

__global__ void w2t_kernel(const float* __restrict__ W, _Float16* __restrict__ Bt) {
    int i = blockIdx.x * 256 + threadIdx.x;   // 65536
    int k = i >> 8, n = i & 255;
    Bt[(size_t)n * kGH + k] = (_Float16)W[(size_t)k * kGH + n];
}

// ---------------------------------------------------------------------------
// Conv1 fused: h2[v] = relu(dinv[v]*(dinv[v]*M11[x[v]] + sum_s dinv[s]*M11[x[s]]) + b1)
// One wave per node, lane handles 4 channels. Output fp16.
// ---------------------------------------------------------------------------
__global__ void aggregate1_kernel(const int* __restrict__ x1, const int* __restrict__ x2,
                                  const float* __restrict__ dinv,
                                  const int* __restrict__ row_ptr, const int* __restrict__ col_idx,
                                  const float* __restrict__ M11, const float* __restrict__ bias,
                                  _Float16* __restrict__ out) {
    int side = blockIdx.y;
    const int* x = side ? x2 : x1;
    const float* dv_ = dinv + side * kN;
    const int* rp = row_ptr + side * (kN + 1);
    const int* ci = col_idx + (size_t)side * kE;
    _Float16* ob = out + (size_t)side * kN * kGH;

    int wave = threadIdx.x >> 6;
    int lane = threadIdx.x & 63;
    int v = blockIdx.x * 4 + wave;
    if (v >= kN) return;
    int c = lane * 4;
    float4 bia = *(const float4*)(bias + c);
    float dv = dv_[v];
    float4 m = *(const float4*)(M11 + x[v] * kGH + c);
    float4 acc = make_float4(dv * m.x, dv * m.y, dv * m.z, dv * m.w);
    int e0 = rp[v], e1 = rp[v + 1];
    for (int e = e0; e < e1; e++) {
        int s = ci[e];
        float ds = dv_[s];
        float4 ms = *(const float4*)(M11 + x[s] * kGH + c);
        acc.x += ds * ms.x; acc.y += ds * ms.y; acc.z += ds * ms.z; acc.w += ds * ms.w;
    }
    half4v o;
    o[0] = (_Float16)fmaxf(dv * acc.x + bia.x, 0.f);
    o[1] = (_Float16)fmaxf(dv * acc.y + bia.y, 0.f);
    o[2] = (_Float16)fmaxf(dv * acc.z + bia.z, 0.f);
    o[3] = (_Float16)fmaxf(dv * acc.w + bia.w, 0.f);
    *(half4v*)(ob + (size_t)v * kGH + c) = o;
}

// ---------------------------------------------------------------------------
// Conv2 GEMM via MFMA f16: hs = dinv ⊙ (h2 @ W2).  A fp16 [N,256], Bt fp16 [256,256]
// (n-major), fp32 accumulate, fp16 out. Block = 4 waves, 64 rows; wave = 16 rows
// x 256 cols = 16 acc tiles of 16x16.
// ---------------------------------------------------------------------------
__launch_bounds__(256)
__global__ void gemm2_mfma_kernel(const _Float16* __restrict__ A,
                                  const _Float16* __restrict__ Bt,
                                  const float* __restrict__ dinv,
                                  _Float16* __restrict__ C) {
    int side = blockIdx.y;
    const _Float16* Ab = A + (size_t)side * kN * kGH;
    const float* db = dinv + (size_t)side * kN;
    _Float16* Cb = C + (size_t)side * kN * kGH;

    int wave = threadIdx.x >> 6, lane = threadIdx.x & 63;
    int quad = lane >> 4, r = lane & 15;
    int row0 = blockIdx.x * 64 + wave * 16;
    int arow = row0 + r;
    if (arow >= kN) arow = kN - 1;        // clamp loads; stores guarded below

    floatx4 acc[16];
    #pragma unroll
    for (int i = 0; i < 16; i++) acc[i] = (floatx4){0.f, 0.f, 0.f, 0.f};

    for (int k0 = 0; k0 < kGH; k0 += 32) {
        half8v afrag = *(const half8v*)(Ab + (size_t)arow * kGH + k0 + quad * 8);
        #pragma unroll
        for (int nt = 0; nt < 16; nt++) {
            half8v bfrag = *(const half8v*)(Bt + (size_t)(nt * 16 + r) * kGH + k0 + quad * 8);
            acc[nt] = __builtin_amdgcn_mfma_f32_16x16x32_f16(afrag, bfrag, acc[nt], 0, 0, 0);
        }
    }
    #pragma unroll
    for (int i = 0; i < 4; i++) {
        int grow = row0 + quad * 4 + i;    // C/D: col=lane&15, row=quad*4+reg
        if (grow >= kN) continue;
        float rs = db[grow];
        #pragma unroll
        for (int nt = 0; nt < 16; nt++) {
            Cb[(size_t)grow * kGH + nt * 16 + r] = (_Float16)(acc[nt][i] * rs);
        }
    }
}

// ---------------------------------------------------------------------------
// Conv2 aggregate: h4[v] = relu(dinv[v]*(hs[v] + sum_s hs[s]) + b2)  (hs fp16)
// ---------------------------------------------------------------------------
__global__ void aggregate2_kernel(const _Float16* __restrict__ hs, const float* __restrict__ dinv,
                                  const int* __restrict__ row_ptr, const int* __restrict__ col_idx,
                                  const float* __restrict__ bias, _Float16* __restrict__ out) {
    int side = blockIdx.y;
    const _Float16* hb = hs + (size_t)side * kN * kGH;
    const float* dv_ = dinv + side * kN;
    const int* rp = row_ptr + side * (kN + 1);
    const int* ci = col_idx + (size_t)side * kE;
    _Float16* ob = out + (size_t)side * kN * kGH;

    int wave = threadIdx.x >> 6;
    int lane = threadIdx.x & 63;
    int v = blockIdx.x * 4 + wave;
    if (v >= kN) return;
    int c = lane * 4;
    float4 bia = *(const float4*)(bias + c);
    float dv = dv_[v];
    half4v hv = *(const half4v*)(hb + (size_t)v * kGH + c);   // self-loop term
    float a0 = (float)hv[0], a1 = (float)hv[1], a2 = (float)hv[2], a3 = (float)hv[3];
    int e0 = rp[v], e1 = rp[v + 1];
    for (int e = e0; e < e1; e++) {
        int s = ci[e];
        half4v h = *(const half4v*)(hb + (size_t)s * kGH + c);
        a0 += (float)h[0]; a1 += (float)h[1]; a2 += (float)h[2]; a3 += (float)h[3];
    }
    half4v o;
    o[0] = (_Float16)fmaxf(dv * a0 + bia.x, 0.f);
    o[1] = (_Float16)fmaxf(dv * a1 + bia.y, 0.f);
    o[2] = (_Float16)fmaxf(dv * a2 + bia.z, 0.f);
    o[3] = (_Float16)fmaxf(dv * a3 + bia.w, 0.f);
    *(half4v*)(ob + (size_t)v * kGH + c) = o;
}

// ---------------------------------------------------------------------------
// Global mean pool (sorted batch -> binary search, atomic-free). fp16 in, fp32 out.
// pooled stacked [2G, GH]: side-0 rows then side-1 rows.
// ---------------------------------------------------------------------------
__global__ void pool_kernel(const _Float16* __restrict__ h,
                            const int* __restrict__ batch1, const int* __restrict__ batch2,
                            float* __restrict__ pooled) {
    int side = blockIdx.y;
    const _Float16* hb = h + (size_t)side * kN * kGH;
    const int* batch = side ? batch2 : batch1;
    int g = blockIdx.x;
    int lo = 0, hi = kN;
    while (lo < hi) { int mid = (lo + hi) >> 1; if (batch[mid] < g) lo = mid + 1; else hi = mid; }
    int start = lo;
    lo = start; hi = kN;
    while (lo < hi) { int mid = (lo + hi) >> 1; if (batch[mid] < g + 1) lo = mid + 1; else hi = mid; }
    int end = lo;
    int c = threadIdx.x;  // 256
    float s = 0.f;
    for (int v = start; v < end; v++) s += (float)hb[(size_t)v * kGH + c];
    float cnt = (float)(end - start);
    pooled[(size_t)(side * kG + g) * kGH + c] = s / fmaxf(cnt, 1.0f);
}

// ---------------------------------------------------------------------------
// Entity embedding gather + relu, both sides stacked [2G, EMB]
// ---------------------------------------------------------------------------
__global__ void ent_gather_kernel(const float* __restrict__ emb,
                                  const int* __restrict__ ent1, const int* __restrict__ ent2,
                                  float* __restrict__ out) {
    int i = blockIdx.x * blockDim.x + threadIdx.x;
    if (i >= 2 * kG * kEMB) return;
    int g = i >> 7, c = i & 127;
    int idx = (g < kG) ? ent1[g] : ent2[g - kG];
    out[i] = fmaxf(emb[(size_t)idx * kEMB + c], 0.f);
}

// ---------------------------------------------------------------------------
// egs = relu(concat(g1,e1) + concat(g2,e2))  with stacked [2G,·] inputs
// ---------------------------------------------------------------------------
__global__ void egs_kernel(const float* __restrict__ gfc, const float* __restrict__ ento,
                           float* __restrict__ egs) {
    int i = blockIdx.x * blockDim.x + threadIdx.x;
    if (i >= kG * kHID) return;
    int g = i >> 9, c = i & 511;
    float v;
    if (c < kGH) v = gfc[(size_t)g * kGH + c] + gfc[(size_t)(g + kG) * kGH + c];
    else         v = ento[(size_t)g * kEH + c - kGH] + ento[(size_t)(g + kG) * kEH + c - kGH];
    egs[i] = fmaxf(v, 0.f);
}

// ---------------------------------------------------------------------------
// Generic tiled fp32 GEMM (tail layers): C = (A@B) [+bias] [relu]
// BM=BN=64, BK=16, 256 threads, 4x4 microtile. K%16==0, N%64==0.
// ---------------------------------------------------------------------------
__launch_bounds__(256)
__global__ void gemm_kernel(const float* __restrict__ A, const float* __restrict__ B,
                            float* __restrict__ C, int M, int N, int K,
                            const float* __restrict__ bias, int relu) {
    __shared__ float As[16][64];
    __shared__ float Bs[16][64];
    int tid = threadIdx.x;
    int tx = tid & 15, ty = tid >> 4;
    int row0 = blockIdx.y * 64, col0 = blockIdx.x * 64;
    float acc[4][4] = {};
    for (int k0 = 0; k0 < K; k0 += 16) {
        {   // A tile 64x16, transposed into LDS
            int r = tid >> 2, seg = tid & 3;
            int gr = row0 + r;
            float4 v = make_float4(0.f, 0.f, 0.f, 0.f);
            if (gr < M) v = *(const float4*)(A + (size_t)gr * K + k0 + seg * 4);
            As[seg * 4 + 0][r] = v.x; As[seg * 4 + 1][r] = v.y;
            As[seg * 4 + 2][r] = v.z; As[seg * 4 + 3][r] = v.w;
        }
        {   // B tile 16x64
            int kr = tid >> 4, c4 = (tid & 15) * 4;
            float4 v = *(const float4*)(B + (size_t)(k0 + kr) * N + col0 + c4);
            *(float4*)&Bs[kr][c4] = v;
        }
        __syncthreads();
        #pragma unroll
        for (int k = 0; k < 16; k++) {
            float a[4], b[4];
            #pragma unroll
            for (int i = 0; i < 4; i++) a[i] = As[k][ty * 4 + i];
            #pragma unroll
            for (int j = 0; j < 4; j++) b[j] = Bs[k][tx * 4 + j];
            #pragma unroll
            for (int i = 0; i < 4; i++)
                #pragma unroll
                for (int j = 0; j < 4; j++)
                    acc[i][j] += a[i] * b[j];
        }
        __syncthreads();
    }
    #pragma unroll
    for (int i = 0; i < 4; i++) {
        int gr = row0 + ty * 4 + i;
        if (gr >= M) continue;
        #pragma unroll
        for (int j = 0; j < 4; j++) {
            int gc = col0 + tx * 4 + j;
            float v = acc[i][j];
            if (bias) v += bias[gc];
            if (relu) v = fmaxf(v, 0.f);
            C[(size_t)gr * N + gc] = v;
        }
    }
}

// ---------------------------------------------------------------------------
// Host launch
// ---------------------------------------------------------------------------
static inline char* carve(char*& p, size_t bytes) {
    char* r = p;
    p += (bytes + 255) & ~(size_t)255;
    return r;
}

extern "C" void kernel_launch(void* const* d_in, const int* in_sizes, int n_in,
                              void* d_out, int out_size, void* d_ws, size_t ws_size,
                              hipStream_t stream) {
    const int*   x1       = (const int*)d_in[0];
    const int*   ei1      = (const int*)d_in[1];
    const int*   ent1     = (const int*)d_in[2];
    const int*   batch1   = (const int*)d_in[3];
    const int*   x2       = (const int*)d_in[4];
    const int*   ei2      = (const int*)d_in[5];
    const int*   ent2     = (const int*)d_in[6];
    const int*   batch2   = (const int*)d_in[7];
    const float* atom_emb = (const float*)d_in[8];
    const float* gW1      = (const float*)d_in[9];
    const float* gb1      = (const float*)d_in[10];
    const float* gW2      = (const float*)d_in[11];
    const float* gb2      = (const float*)d_in[12];
    const float* fcW      = (const float*)d_in[13];
    const float* fcb      = (const float*)d_in[14];
    const float* ent_emb  = (const float*)d_in[15];
    const float* eW1      = (const float*)d_in[16];
    const float* eb1      = (const float*)d_in[17];
    const float* eW2      = (const float*)d_in[18];
    const float* eb2      = (const float*)d_in[19];
    const float* dW1      = (const float*)d_in[20];
    const float* db1      = (const float*)d_in[21];
    const float* dW2      = (const float*)d_in[22];
    const float* db2      = (const float*)d_in[23];
    const float* dW3      = (const float*)d_in[24];
    const float* db3      = (const float*)d_in[25];
    float* out = (float*)d_out;

    // Workspace carve (h4 reuses h2 buffer: h2 is dead after gemm2)
    char* p = (char*)d_ws;
    _Float16* h2_h   = (_Float16*)carve(p, (size_t)2 * kN * kGH * 2);  // also h4
    _Float16* hs_h   = (_Float16*)carve(p, (size_t)2 * kN * kGH * 2);
    int*   col_idx = (int*)  carve(p, (size_t)2 * kE * 4);
    int*   row_ptr = (int*)  carve(p, (size_t)2 * (kN + 1) * 4);
    int*   counts  = (int*)  carve(p, (size_t)2 * kN * 4);
    int*   fillc   = (int*)  carve(p, (size_t)2 * kN * 4);
    float* dinv    = (float*)carve(p, (size_t)2 * kN * 4);
    int*   bsum    = (int*)  carve(p, (size_t)2 * kNB * 4);
    int*   boff    = (int*)  carve(p, (size_t)2 * kNB * 4);
    float* M11     = (float*)carve(p, 11 * kGH * 4);
    _Float16* w2t  = (_Float16*)carve(p, (size_t)kGH * kGH * 2);
    float* pooled  = (float*)carve(p, (size_t)2 * kG * kGH * 4);   // stacked both sides
    float* gfc     = (float*)carve(p, (size_t)2 * kG * kGH * 4);
    float* e0      = (float*)carve(p, (size_t)2 * kG * kEMB * 4);
    float* etmp    = (float*)carve(p, (size_t)2 * kG * kEH * 4);
    float* ento    = (float*)carve(p, (size_t)2 * kG * kEH * 4);
    float* egs     = (float*)carve(p, (size_t)kG * kHID * 4);
    float* dh1     = (float*)carve(p, (size_t)kG * kHID * 4);
    float* dh2     = (float*)carve(p, (size_t)kG * kHID * 4);

    // Precompute: M11 = atom_emb@gW1 (conv1 GEMM -> 11-row table); W2^T fp16
    m11_kernel<<<1, 256, 0, stream>>>(atom_emb, gW1, M11);
    w2t_kernel<<<kGH * kGH / 256, 256, 0, stream>>>(gW2, w2t);

    // --- Graph structure, both sides (gridDim.y = 2) ---
    hipMemsetAsync(counts, 0, (size_t)2 * kN * 4, stream);
    hipMemsetAsync(fillc, 0, (size_t)2 * kN * 4, stream);
    deg_kernel<<<dim3(kE / 256, 2), 256, 0, stream>>>(ei1 + kE, ei2 + kE, counts);
    bsum_kernel<<<dim3(kNB, 2), 256, 0, stream>>>(counts, bsum);
    bscan_kernel<<<2, 256, 0, stream>>>(bsum, boff);
    scanf_kernel<<<dim3(kNB, 2), 256, 0, stream>>>(counts, boff, row_ptr);
    dinv_kernel<<<dim3((kN + 255) / 256, 2), 256, 0, stream>>>(counts, dinv);
    fill_kernel<<<dim3(kE / 256, 2), 256, 0, stream>>>(ei1, ei2, row_ptr, fillc, col_idx);

    // --- Conv1 fused (embed gather + M11 lookup + aggregate + bias + relu) -> fp16 h2 ---
    aggregate1_kernel<<<dim3((kN + 3) / 4, 2), 256, 0, stream>>>(x1, x2, dinv, row_ptr, col_idx,
                                                                 M11, gb1, h2_h);
    // --- Conv2 GEMM (MFMA f16): hs = dinv ⊙ (h2 @ W2) ---
    gemm2_mfma_kernel<<<dim3((kN + 63) / 64, 2), 256, 0, stream>>>(h2_h, w2t, dinv, hs_h);
    // --- Conv2 aggregate -> h4 (reuses h2 buffer) ---
    aggregate2_kernel<<<dim3((kN + 3) / 4, 2), 256, 0, stream>>>(hs_h, dinv, row_ptr, col_idx,
                                                                 gb2, h2_h);
    // --- Mean pool -> stacked [2G, GH] fp32 ---
    pool_kernel<<<dim3(kG, 2), 256, 0, stream>>>(h2_h, batch1, batch2, pooled);

    // --- fc on pooled (both sides in one GEMM, no relu) ---
    gemm_kernel<<<dim3(kGH / 64, 2 * kG / 64), 256, 0, stream>>>(pooled, fcW, gfc,
                                                                 2 * kG, kGH, kGH, fcb, 0);

    // --- Entity encoders (both sides stacked) ---
    ent_gather_kernel<<<(2 * kG * kEMB + 255) / 256, 256, 0, stream>>>(ent_emb, ent1, ent2, e0);
    gemm_kernel<<<dim3(kEH / 64, 2 * kG / 64), 256, 0, stream>>>(e0, eW1, etmp,
                                                                 2 * kG, kEH, kEMB, eb1, 1);
    gemm_kernel<<<dim3(kEH / 64, 2 * kG / 64), 256, 0, stream>>>(etmp, eW2, ento,
                                                                 2 * kG, kEH, kEH, eb2, 1);

    // --- Decoder ---
    egs_kernel<<<(kG * kHID + 255) / 256, 256, 0, stream>>>(gfc, ento, egs);
    gemm_kernel<<<dim3(kHID / 64, kG / 64), 256, 0, stream>>>(egs, dW1, dh1,
                                                              kG, kHID, kHID, db1, 1);
    gemm_kernel<<<dim3(kHID / 64, kG / 64), 256, 0, stream>>>(dh1, dW2, dh2,
                                                              kG, kHID, kHID, db2, 1);
    gemm_kernel<<<dim3(kOUT / 64, kG / 64), 256, 0, stream>>>(dh2, dW3, out,
                                                              kG, kOUT, kHID, db3, 0);
}

// Round 3
// 863.240 us; speedup vs baseline: 1.5679x; 1.0917x over previous
//
#include <hip/hip_runtime.h>
#include <hip/hip_fp16.h>

// Problem constants
static constexpr int kN = 50000;      // nodes per side
static constexpr int kE = 800000;     // edges per side
static constexpr int kG = 1024;       // graphs per batch
static constexpr int kEMB = 128;
static constexpr int kGH = 256;
static constexpr int kEH = 256;
static constexpr int kOUT = 128;
static constexpr int kHID = 512;
static constexpr int kNB = (kN + 255) / 256;   // 196 scan chunks per side

typedef __attribute__((ext_vector_type(8))) _Float16 half8v;
typedef __attribute__((ext_vector_type(4))) _Float16 half4v;
typedef __attribute__((ext_vector_type(4))) float floatx4;

// ---------------------------------------------------------------------------
// Graph structure: degree count (both sides via blockIdx.y)
// ---------------------------------------------------------------------------
__global__ void deg_kernel(const int* __restrict__ dst1, const int* __restrict__ dst2,
                           int* __restrict__ counts) {
    int side = blockIdx.y;
    const int* dst = side ? dst2 : dst1;
    int* c = counts + side * kN;
    int i = blockIdx.x * blockDim.x + threadIdx.x;
    if (i < kE) atomicAdd(&c[dst[i]], 1);
}

// Per-chunk sums (196 chunks per side)
__global__ void bsum_kernel(const int* __restrict__ counts, int* __restrict__ bsum) {
    int side = blockIdx.y;
    const int* c = counts + side * kN;
    int i = blockIdx.x * 256 + threadIdx.x;
    int v = (i < kN) ? c[i] : 0;
    #pragma unroll
    for (int o = 32; o; o >>= 1) v += __shfl_down(v, o);
    __shared__ int ws[4];
    if ((threadIdx.x & 63) == 0) ws[threadIdx.x >> 6] = v;
    __syncthreads();
    if (threadIdx.x == 0) bsum[side * kNB + blockIdx.x] = ws[0] + ws[1] + ws[2] + ws[3];
}

// Exclusive scan of the chunk sums (one block per side)
__global__ void bscan_kernel(const int* __restrict__ bsum, int* __restrict__ boff) {
    int side = blockIdx.x;
    __shared__ int s[256];
    int t = threadIdx.x;
    int v = (t < kNB) ? bsum[side * kNB + t] : 0;
    s[t] = v;
    __syncthreads();
    for (int o = 1; o < 256; o <<= 1) {
        int u = (t >= o) ? s[t - o] : 0;
        __syncthreads();
        s[t] += u;
        __syncthreads();
    }
    if (t < kNB) boff[side * kNB + t] = s[t] - v;   // exclusive
}

// Final: local inclusive scan per chunk + chunk offset -> row_ptr.
// Fused: dinv = rsqrt(deg+1) and xd[v] = (x[v], bits(dinv[v])).
__global__ void scanf_kernel(const int* __restrict__ counts, const int* __restrict__ boff,
                             int* __restrict__ row_ptr, float* __restrict__ dinv,
                             int2* __restrict__ xd,
                             const int* __restrict__ x1, const int* __restrict__ x2) {
    int side = blockIdx.y;
    const int* c = counts + side * kN;
    int* rp = row_ptr + side * (kN + 1);
    int t = threadIdx.x;
    int i = blockIdx.x * 256 + t;
    __shared__ int s[256];
    int v = (i < kN) ? c[i] : 0;
    s[t] = v;
    __syncthreads();
    for (int o = 1; o < 256; o <<= 1) {
        int u = (t >= o) ? s[t - o] : 0;
        __syncthreads();
        s[t] += u;
        __syncthreads();
    }
    if (i < kN) {
        rp[i + 1] = boff[side * kNB + blockIdx.x] + s[t];
        float dv = rsqrtf((float)(v + 1));           // +1 self-loop
        dinv[side * kN + i] = dv;
        const int* x = side ? x2 : x1;
        xd[side * kN + i] = make_int2(x[i], __float_as_int(dv));
    }
    if (i == 0) rp[0] = 0;
}

__global__ void fill_kernel(const int* __restrict__ ei1, const int* __restrict__ ei2,
                            const int* __restrict__ row_ptr, int* __restrict__ fillc,
                            int* __restrict__ col_idx) {
    int side = blockIdx.y;
    const int* ei = side ? ei2 : ei1;
    const int* src = ei;
    const int* dst = ei + kE;
    const int* rp = row_ptr + side * (kN + 1);
    int* fc = fillc + side * kN;
    int* ci = col_idx + (size_t)side * kE;
    int i = blockIdx.x * blockDim.x + threadIdx.x;
    if (i < kE) {
        int d = dst[i];
        int pos = rp[d] + atomicAdd(&fc[d], 1);
        ci[pos] = src[i];
    }
}

// ---------------------------------------------------------------------------
// M11 = atom_emb @ gW1  [11,256];  W2T fp16 transpose  [n][k]
// ---------------------------------------------------------------------------
__global__ void m11_kernel(const float* __restrict__ atom_emb, const float* __restrict__ gW1,
                           float* __restrict__ M11) {
    int c = threadIdx.x;  // 256 channels
    for (int r = 0; r < 11; r++) {
        float s = 0.f;
        for (int k = 0; k < kEMB; k++) s += atom_emb[r * kEMB + k] * gW1[k * kGH + c];
        M11[r * kGH + c] = s;
    }
}

__global__ void w2t_kernel(const float* __restrict__ W, _Float16* __restrict__ Bt) {
    int i = blockIdx.x * 256 + threadIdx.x;   // 65536
    int k = i >> 8, n = i & 255;
    Bt[(size_t)n * kGH + k] = (_Float16)W[(size_t)k * kGH + n];
}

// ---------------------------------------------------------------------------
// Conv1 fused: h2[v] = relu(dinv[v]*(dinv[v]*M11[x[v]] + sum_s dinv[s]*M11[x[s]]) + b1)
// One wave per node, lane covers 4 channels. 8-wide ILP: coalesced edge-index
// preload via lanes + __shfl broadcast, 8 concurrent xd gathers.
// ---------------------------------------------------------------------------
__global__ void aggregate1_kernel(const int2* __restrict__ xd,
                                  const int* __restrict__ row_ptr, const int* __restrict__ col_idx,
                                  const float* __restrict__ M11, const float* __restrict__ bias,
                                  _Float16* __restrict__ out) {
    int side = blockIdx.y;
    const int2* xdb = xd + (size_t)side * kN;
    const int* rp = row_ptr + side * (kN + 1);
    const int* ci = col_idx + (size_t)side * kE;
    _Float16* ob = out + (size_t)side * kN * kGH;

    int wave = threadIdx.x >> 6;
    int lane = threadIdx.x & 63;
    int v = blockIdx.x * 4 + wave;
    if (v >= kN) return;
    int c = lane * 4;
    float4 bia = *(const float4*)(bias + c);
    int2 xv = xdb[v];
    float dv = __int_as_float(xv.y);
    float4 m = *(const float4*)(M11 + xv.x * kGH + c);
    float4 acc = make_float4(dv * m.x, dv * m.y, dv * m.z, dv * m.w);
    int e0 = rp[v], e1 = rp[v + 1];
    for (int base = e0; base < e1; base += 64) {
        int cnt = min(64, e1 - base);
        int idxl = (base + lane < e1) ? ci[base + lane] : 0;
        int j = 0;
        for (; j + 8 <= cnt; j += 8) {
            int2 xs[8];
            #pragma unroll
            for (int u = 0; u < 8; u++) xs[u] = xdb[__shfl(idxl, j + u)];
            #pragma unroll
            for (int u = 0; u < 8; u++) {
                float ds = __int_as_float(xs[u].y);
                float4 ms = *(const float4*)(M11 + xs[u].x * kGH + c);
                acc.x += ds * ms.x; acc.y += ds * ms.y;
                acc.z += ds * ms.z; acc.w += ds * ms.w;
            }
        }
        for (; j < cnt; j++) {
            int2 xs = xdb[__shfl(idxl, j)];
            float ds = __int_as_float(xs.y);
            float4 ms = *(const float4*)(M11 + xs.x * kGH + c);
            acc.x += ds * ms.x; acc.y += ds * ms.y;
            acc.z += ds * ms.z; acc.w += ds * ms.w;
        }
    }
    half4v o;
    o[0] = (_Float16)fmaxf(dv * acc.x + bia.x, 0.f);
    o[1] = (_Float16)fmaxf(dv * acc.y + bia.y, 0.f);
    o[2] = (_Float16)fmaxf(dv * acc.z + bia.z, 0.f);
    o[3] = (_Float16)fmaxf(dv * acc.w + bia.w, 0.f);
    *(half4v*)(ob + (size_t)v * kGH + c) = o;
}

// ---------------------------------------------------------------------------
// Conv2 GEMM via MFMA f16: hs = dinv ⊙ (h2 @ W2)
// ---------------------------------------------------------------------------
__launch_bounds__(256)
__global__ void gemm2_mfma_kernel(const _Float16* __restrict__ A,
                                  const _Float16* __restrict__ Bt,
                                  const float* __restrict__ dinv,
                                  _Float16* __restrict__ C) {
    int side = blockIdx.y;
    const _Float16* Ab = A + (size_t)side * kN * kGH;
    const float* db = dinv + (size_t)side * kN;
    _Float16* Cb = C + (size_t)side * kN * kGH;

    int wave = threadIdx.x >> 6, lane = threadIdx.x & 63;
    int quad = lane >> 4, r = lane & 15;
    int row0 = blockIdx.x * 64 + wave * 16;
    int arow = row0 + r;
    if (arow >= kN) arow = kN - 1;        // clamp loads; stores guarded below

    floatx4 acc[16];
    #pragma unroll
    for (int i = 0; i < 16; i++) acc[i] = (floatx4){0.f, 0.f, 0.f, 0.f};

    for (int k0 = 0; k0 < kGH; k0 += 32) {
        half8v afrag = *(const half8v*)(Ab + (size_t)arow * kGH + k0 + quad * 8);
        #pragma unroll
        for (int nt = 0; nt < 16; nt++) {
            half8v bfrag = *(const half8v*)(Bt + (size_t)(nt * 16 + r) * kGH + k0 + quad * 8);
            acc[nt] = __builtin_amdgcn_mfma_f32_16x16x32_f16(afrag, bfrag, acc[nt], 0, 0, 0);
        }
    }
    #pragma unroll
    for (int i = 0; i < 4; i++) {
        int grow = row0 + quad * 4 + i;    // C/D: col=lane&15, row=quad*4+reg
        if (grow >= kN) continue;
        float rs = db[grow];
        #pragma unroll
        for (int nt = 0; nt < 16; nt++) {
            Cb[(size_t)grow * kGH + nt * 16 + r] = (_Float16)(acc[nt][i] * rs);
        }
    }
}

// ---------------------------------------------------------------------------
// Conv2 aggregate: h4[v] = relu(dinv[v]*(hs[v] + sum_s hs[s]) + b2)  (hs fp16)
// 8-wide ILP gather version.
// ---------------------------------------------------------------------------
__global__ void aggregate2_kernel(const _Float16* __restrict__ hs, const float* __restrict__ dinv,
                                  const int* __restrict__ row_ptr, const int* __restrict__ col_idx,
                                  const float* __restrict__ bias, _Float16* __restrict__ out) {
    int side = blockIdx.y;
    const _Float16* hb = hs + (size_t)side * kN * kGH;
    const float* dv_ = dinv + side * kN;
    const int* rp = row_ptr + side * (kN + 1);
    const int* ci = col_idx + (size_t)side * kE;
    _Float16* ob = out + (size_t)side * kN * kGH;

    int wave = threadIdx.x >> 6;
    int lane = threadIdx.x & 63;
    int v = blockIdx.x * 4 + wave;
    if (v >= kN) return;
    int c = lane * 4;
    float4 bia = *(const float4*)(bias + c);
    float dv = dv_[v];
    half4v hv = *(const half4v*)(hb + (size_t)v * kGH + c);   // self-loop term
    float a0 = (float)hv[0], a1 = (float)hv[1], a2 = (float)hv[2], a3 = (float)hv[3];
    int e0 = rp[v], e1 = rp[v + 1];
    for (int base = e0; base < e1; base += 64) {
        int cnt = min(64, e1 - base);
        int idxl = (base + lane < e1) ? ci[base + lane] : 0;
        int j = 0;
        for (; j + 8 <= cnt; j += 8) {
            half4v h[8];
            #pragma unroll
            for (int u = 0; u < 8; u++)
                h[u] = *(const half4v*)(hb + (size_t)__shfl(idxl, j + u) * kGH + c);
            #pragma unroll
            for (int u = 0; u < 8; u++) {
                a0 += (float)h[u][0]; a1 += (float)h[u][1];
                a2 += (float)h[u][2]; a3 += (float)h[u][3];
            }
        }
        for (; j < cnt; j++) {
            half4v h = *(const half4v*)(hb + (size_t)__shfl(idxl, j) * kGH + c);
            a0 += (float)h[0]; a1 += (float)h[1]; a2 += (float)h[2]; a3 += (float)h[3];
        }
    }
    half4v o;
    o[0] = (_Float16)fmaxf(dv * a0 + bia.x, 0.f);
    o[1] = (_Float16)fmaxf(dv * a1 + bia.y, 0.f);
    o[2] = (_Float16)fmaxf(dv * a2 + bia.z, 0.f);
    o[3] = (_Float16)fmaxf(dv * a3 + bia.w, 0.f);
    *(half4v*)(ob + (size_t)v * kGH + c) = o;
}

// ---------------------------------------------------------------------------
// Global mean pool (sorted batch -> binary search, atomic-free). fp16 in, fp32 out.
// pooled stacked [2G, GH].
// ---------------------------------------------------------------------------
__global__ void pool_kernel(const _Float16* __restrict__ h,
                            const int* __restrict__ batch1, const int* __restrict__ batch2,
                            float* __restrict__ pooled) {
    int side = blockIdx.y;
    const _Float16* hb = h + (size_t)side * kN * kGH;
    const int* batch = side ? batch2 : batch1;
    int g = blockIdx.x;
    int lo = 0, hi = kN;
    while (lo < hi) { int mid = (lo + hi) >> 1; if (batch[mid] < g) lo = mid + 1; else hi = mid; }
    int start = lo;
    lo = start; hi = kN;
    while (lo < hi) { int mid = (lo + hi) >> 1; if (batch[mid] < g + 1) lo = mid + 1; else hi = mid; }
    int end = lo;
    int c = threadIdx.x;  // 256
    float s = 0.f;
    for (int v = start; v < end; v++) s += (float)hb[(size_t)v * kGH + c];
    float cnt = (float)(end - start);
    pooled[(size_t)(side * kG + g) * kGH + c] = s / fmaxf(cnt, 1.0f);
}

// ---------------------------------------------------------------------------
// Entity embedding gather + relu, both sides stacked [2G, EMB]
// ---------------------------------------------------------------------------
__global__ void ent_gather_kernel(const float* __restrict__ emb,
                                  const int* __restrict__ ent1, const int* __restrict__ ent2,
                                  float* __restrict__ out) {
    int i = blockIdx.x * blockDim.x + threadIdx.x;
    if (i >= 2 * kG * kEMB) return;
    int g = i >> 7, c = i & 127;
    int idx = (g < kG) ? ent1[g] : ent2[g - kG];
    out[i] = fmaxf(emb[(size_t)idx * kEMB + c], 0.f);
}

// ---------------------------------------------------------------------------
// egs = relu(concat(g1,e1) + concat(g2,e2))  with stacked [2G,·] inputs
// ---------------------------------------------------------------------------
__global__ void egs_kernel(const float* __restrict__ gfc, const float* __restrict__ ento,
                           float* __restrict__ egs) {
    int i = blockIdx.x * blockDim.x + threadIdx.x;
    if (i >= kG * kHID) return;
    int g = i >> 9, c = i & 511;
    float v;
    if (c < kGH) v = gfc[(size_t)g * kGH + c] + gfc[(size_t)(g + kG) * kGH + c];
    else         v = ento[(size_t)g * kEH + c - kGH] + ento[(size_t)(g + kG) * kEH + c - kGH];
    egs[i] = fmaxf(v, 0.f);
}

// ---------------------------------------------------------------------------
// Generic tiled fp32 GEMM (tail layers): C = (A@B) [+bias] [relu]
// ---------------------------------------------------------------------------
__launch_bounds__(256)
__global__ void gemm_kernel(const float* __restrict__ A, const float* __restrict__ B,
                            float* __restrict__ C, int M, int N, int K,
                            const float* __restrict__ bias, int relu) {
    __shared__ float As[16][64];
    __shared__ float Bs[16][64];
    int tid = threadIdx.x;
    int tx = tid & 15, ty = tid >> 4;
    int row0 = blockIdx.y * 64, col0 = blockIdx.x * 64;
    float acc[4][4] = {};
    for (int k0 = 0; k0 < K; k0 += 16) {
        {   // A tile 64x16, transposed into LDS
            int r = tid >> 2, seg = tid & 3;
            int gr = row0 + r;
            float4 v = make_float4(0.f, 0.f, 0.f, 0.f);
            if (gr < M) v = *(const float4*)(A + (size_t)gr * K + k0 + seg * 4);
            As[seg * 4 + 0][r] = v.x; As[seg * 4 + 1][r] = v.y;
            As[seg * 4 + 2][r] = v.z; As[seg * 4 + 3][r] = v.w;
        }
        {   // B tile 16x64
            int kr = tid >> 4, c4 = (tid & 15) * 4;
            float4 v = *(const float4*)(B + (size_t)(k0 + kr) * N + col0 + c4);
            *(float4*)&Bs[kr][c4] = v;
        }
        __syncthreads();
        #pragma unroll
        for (int k = 0; k < 16; k++) {
            float a[4], b[4];
            #pragma unroll
            for (int i = 0; i < 4; i++) a[i] = As[k][ty * 4 + i];
            #pragma unroll
            for (int j = 0; j < 4; j++) b[j] = Bs[k][tx * 4 + j];
            #pragma unroll
            for (int i = 0; i < 4; i++)
                #pragma unroll
                for (int j = 0; j < 4; j++)
                    acc[i][j] += a[i] * b[j];
        }
        __syncthreads();
    }
    #pragma unroll
    for (int i = 0; i < 4; i++) {
        int gr = row0 + ty * 4 + i;
        if (gr >= M) continue;
        #pragma unroll
        for (int j = 0; j < 4; j++) {
            int gc = col0 + tx * 4 + j;
            float v = acc[i][j];
            if (bias) v += bias[gc];
            if (relu) v = fmaxf(v, 0.f);
            C[(size_t)gr * N + gc] = v;
        }
    }
}

// ---------------------------------------------------------------------------
// Host launch
// ---------------------------------------------------------------------------
static inline char* carve(char*& p, size_t bytes) {
    char* r = p;
    p += (bytes + 255) & ~(size_t)255;
    return r;
}

extern "C" void kernel_launch(void* const* d_in, const int* in_sizes, int n_in,
                              void* d_out, int out_size, void* d_ws, size_t ws_size,
                              hipStream_t stream) {
    const int*   x1       = (const int*)d_in[0];
    const int*   ei1      = (const int*)d_in[1];
    const int*   ent1     = (const int*)d_in[2];
    const int*   batch1   = (const int*)d_in[3];
    const int*   x2       = (const int*)d_in[4];
    const int*   ei2      = (const int*)d_in[5];
    const int*   ent2     = (const int*)d_in[6];
    const int*   batch2   = (const int*)d_in[7];
    const float* atom_emb = (const float*)d_in[8];
    const float* gW1      = (const float*)d_in[9];
    const float* gb1      = (const float*)d_in[10];
    const float* gW2      = (const float*)d_in[11];
    const float* gb2      = (const float*)d_in[12];
    const float* fcW      = (const float*)d_in[13];
    const float* fcb      = (const float*)d_in[14];
    const float* ent_emb  = (const float*)d_in[15];
    const float* eW1      = (const float*)d_in[16];
    const float* eb1      = (const float*)d_in[17];
    const float* eW2      = (const float*)d_in[18];
    const float* eb2      = (const float*)d_in[19];
    const float* dW1      = (const float*)d_in[20];
    const float* db1      = (const float*)d_in[21];
    const float* dW2      = (const float*)d_in[22];
    const float* db2      = (const float*)d_in[23];
    const float* dW3      = (const float*)d_in[24];
    const float* db3      = (const float*)d_in[25];
    float* out = (float*)d_out;

    // Workspace carve (h4 reuses h2 buffer: h2 is dead after gemm2)
    char* p = (char*)d_ws;
    _Float16* h2_h   = (_Float16*)carve(p, (size_t)2 * kN * kGH * 2);  // also h4
    _Float16* hs_h   = (_Float16*)carve(p, (size_t)2 * kN * kGH * 2);
    int*   col_idx = (int*)  carve(p, (size_t)2 * kE * 4);
    int*   row_ptr = (int*)  carve(p, (size_t)2 * (kN + 1) * 4);
    int*   counts  = (int*)  carve(p, (size_t)2 * kN * 4);
    int*   fillc   = (int*)  carve(p, (size_t)2 * kN * 4);
    float* dinv    = (float*)carve(p, (size_t)2 * kN * 4);
    int2*  xd      = (int2*) carve(p, (size_t)2 * kN * 8);
    int*   bsum    = (int*)  carve(p, (size_t)2 * kNB * 4);
    int*   boff    = (int*)  carve(p, (size_t)2 * kNB * 4);
    float* M11     = (float*)carve(p, 11 * kGH * 4);
    _Float16* w2t  = (_Float16*)carve(p, (size_t)kGH * kGH * 2);
    float* pooled  = (float*)carve(p, (size_t)2 * kG * kGH * 4);   // stacked both sides
    float* gfc     = (float*)carve(p, (size_t)2 * kG * kGH * 4);
    float* e0      = (float*)carve(p, (size_t)2 * kG * kEMB * 4);
    float* etmp    = (float*)carve(p, (size_t)2 * kG * kEH * 4);
    float* ento    = (float*)carve(p, (size_t)2 * kG * kEH * 4);
    float* egs     = (float*)carve(p, (size_t)kG * kHID * 4);
    float* dh1     = (float*)carve(p, (size_t)kG * kHID * 4);
    float* dh2     = (float*)carve(p, (size_t)kG * kHID * 4);

    // Precompute: M11 = atom_emb@gW1; W2^T fp16
    m11_kernel<<<1, 256, 0, stream>>>(atom_emb, gW1, M11);
    w2t_kernel<<<kGH * kGH / 256, 256, 0, stream>>>(gW2, w2t);

    // --- Graph structure, both sides (gridDim.y = 2) ---
    hipMemsetAsync(counts, 0, (size_t)2 * kN * 4, stream);
    hipMemsetAsync(fillc, 0, (size_t)2 * kN * 4, stream);
    deg_kernel<<<dim3(kE / 256, 2), 256, 0, stream>>>(ei1 + kE, ei2 + kE, counts);
    bsum_kernel<<<dim3(kNB, 2), 256, 0, stream>>>(counts, bsum);
    bscan_kernel<<<2, 256, 0, stream>>>(bsum, boff);
    scanf_kernel<<<dim3(kNB, 2), 256, 0, stream>>>(counts, boff, row_ptr, dinv, xd, x1, x2);
    fill_kernel<<<dim3(kE / 256, 2), 256, 0, stream>>>(ei1, ei2, row_ptr, fillc, col_idx);

    // --- Conv1 fused -> fp16 h2 ---
    aggregate1_kernel<<<dim3((kN + 3) / 4, 2), 256, 0, stream>>>(xd, row_ptr, col_idx,
                                                                 M11, gb1, h2_h);
    // --- Conv2 GEMM (MFMA f16): hs = dinv ⊙ (h2 @ W2) ---
    gemm2_mfma_kernel<<<dim3((kN + 63) / 64, 2), 256, 0, stream>>>(h2_h, w2t, dinv, hs_h);
    // --- Conv2 aggregate -> h4 (reuses h2 buffer) ---
    aggregate2_kernel<<<dim3((kN + 3) / 4, 2), 256, 0, stream>>>(hs_h, dinv, row_ptr, col_idx,
                                                                 gb2, h2_h);
    // --- Mean pool -> stacked [2G, GH] fp32 ---
    pool_kernel<<<dim3(kG, 2), 256, 0, stream>>>(h2_h, batch1, batch2, pooled);

    // --- fc on pooled (both sides in one GEMM, no relu) ---
    gemm_kernel<<<dim3(kGH / 64, 2 * kG / 64), 256, 0, stream>>>(pooled, fcW, gfc,
                                                                 2 * kG, kGH, kGH, fcb, 0);

    // --- Entity encoders (both sides stacked) ---
    ent_gather_kernel<<<(2 * kG * kEMB + 255) / 256, 256, 0, stream>>>(ent_emb, ent1, ent2, e0);
    gemm_kernel<<<dim3(kEH / 64, 2 * kG / 64), 256, 0, stream>>>(e0, eW1, etmp,
                                                                 2 * kG, kEH, kEMB, eb1, 1);
    gemm_kernel<<<dim3(kEH / 64, 2 * kG / 64), 256, 0, stream>>>(etmp, eW2, ento,
                                                                 2 * kG, kEH, kEH, eb2, 1);

    // --- Decoder ---
    egs_kernel<<<(kG * kHID + 255) / 256, 256, 0, stream>>>(gfc, ento, egs);
    gemm_kernel<<<dim3(kHID / 64, kG / 64), 256, 0, stream>>>(egs, dW1, dh1,
                                                              kG, kHID, kHID, db1, 1);
    gemm_kernel<<<dim3(kHID / 64, kG / 64), 256, 0, stream>>>(dh1, dW2, dh2,
                                                              kG, kHID, kHID, db2, 1);
    gemm_kernel<<<dim3(kOUT / 64, kG / 64), 256, 0, stream>>>(dh2, dW3, out,
                                                              kG, kOUT, kHID, db3, 0);
}

// Round 4
// 789.646 us; speedup vs baseline: 1.7141x; 1.0932x over previous
//
#include <hip/hip_runtime.h>
#include <hip/hip_fp16.h>

// Problem constants
static constexpr int kN = 50000;      // nodes per side
static constexpr int kE = 800000;     // edges per side
static constexpr int kG = 1024;       // graphs per batch
static constexpr int kEMB = 128;
static constexpr int kGH = 256;
static constexpr int kEH = 256;
static constexpr int kOUT = 128;
static constexpr int kHID = 512;
static constexpr int kNB = (kN + 255) / 256;   // 196 scan chunks per side

typedef __attribute__((ext_vector_type(8))) _Float16 half8v;
typedef __attribute__((ext_vector_type(4))) _Float16 half4v;
typedef __attribute__((ext_vector_type(4))) float floatx4;

// ---------------------------------------------------------------------------
// Graph structure: degree count (both sides via blockIdx.y)
// ---------------------------------------------------------------------------
__global__ void deg_kernel(const int* __restrict__ dst1, const int* __restrict__ dst2,
                           int* __restrict__ counts) {
    int side = blockIdx.y;
    const int* dst = side ? dst2 : dst1;
    int* c = counts + side * kN;
    int i = blockIdx.x * blockDim.x + threadIdx.x;
    if (i < kE) atomicAdd(&c[dst[i]], 1);
}

// Per-chunk sums (196 chunks per side)
__global__ void bsum_kernel(const int* __restrict__ counts, int* __restrict__ bsum) {
    int side = blockIdx.y;
    const int* c = counts + side * kN;
    int i = blockIdx.x * 256 + threadIdx.x;
    int v = (i < kN) ? c[i] : 0;
    #pragma unroll
    for (int o = 32; o; o >>= 1) v += __shfl_down(v, o);
    __shared__ int ws[4];
    if ((threadIdx.x & 63) == 0) ws[threadIdx.x >> 6] = v;
    __syncthreads();
    if (threadIdx.x == 0) bsum[side * kNB + blockIdx.x] = ws[0] + ws[1] + ws[2] + ws[3];
}

// Exclusive scan of the chunk sums (one block per side)
__global__ void bscan_kernel(const int* __restrict__ bsum, int* __restrict__ boff) {
    int side = blockIdx.x;
    __shared__ int s[256];
    int t = threadIdx.x;
    int v = (t < kNB) ? bsum[side * kNB + t] : 0;
    s[t] = v;
    __syncthreads();
    for (int o = 1; o < 256; o <<= 1) {
        int u = (t >= o) ? s[t - o] : 0;
        __syncthreads();
        s[t] += u;
        __syncthreads();
    }
    if (t < kNB) boff[side * kNB + t] = s[t] - v;   // exclusive
}

// Final: local inclusive scan per chunk + chunk offset -> row_ptr.
// Fused: dinv = rsqrt(deg+1) and xd[v] = (x[v], bits(dinv[v])).
__global__ void scanf_kernel(const int* __restrict__ counts, const int* __restrict__ boff,
                             int* __restrict__ row_ptr, float* __restrict__ dinv,
                             int2* __restrict__ xd,
                             const int* __restrict__ x1, const int* __restrict__ x2) {
    int side = blockIdx.y;
    const int* c = counts + side * kN;
    int* rp = row_ptr + side * (kN + 1);
    int t = threadIdx.x;
    int i = blockIdx.x * 256 + t;
    __shared__ int s[256];
    int v = (i < kN) ? c[i] : 0;
    s[t] = v;
    __syncthreads();
    for (int o = 1; o < 256; o <<= 1) {
        int u = (t >= o) ? s[t - o] : 0;
        __syncthreads();
        s[t] += u;
        __syncthreads();
    }
    if (i < kN) {
        rp[i + 1] = boff[side * kNB + blockIdx.x] + s[t];
        float dv = rsqrtf((float)(v + 1));           // +1 self-loop
        dinv[side * kN + i] = dv;
        const int* x = side ? x2 : x1;
        xd[side * kN + i] = make_int2(x[i], __float_as_int(dv));
    }
    if (i == 0) rp[0] = 0;
}

__global__ void fill_kernel(const int* __restrict__ ei1, const int* __restrict__ ei2,
                            const int* __restrict__ row_ptr, int* __restrict__ fillc,
                            int* __restrict__ col_idx) {
    int side = blockIdx.y;
    const int* ei = side ? ei2 : ei1;
    const int* src = ei;
    const int* dst = ei + kE;
    const int* rp = row_ptr + side * (kN + 1);
    int* fc = fillc + side * kN;
    int* ci = col_idx + (size_t)side * kE;
    int i = blockIdx.x * blockDim.x + threadIdx.x;
    if (i < kE) {
        int d = dst[i];
        int pos = rp[d] + atomicAdd(&fc[d], 1);
        ci[pos] = src[i];
    }
}

// ---------------------------------------------------------------------------
// M11 = atom_emb @ gW1  [11,256];  W2T fp16 transpose  [n][k]
// ---------------------------------------------------------------------------
__global__ void m11_kernel(const float* __restrict__ atom_emb, const float* __restrict__ gW1,
                           float* __restrict__ M11) {
    int c = threadIdx.x;  // 256 channels
    for (int r = 0; r < 11; r++) {
        float s = 0.f;
        for (int k = 0; k < kEMB; k++) s += atom_emb[r * kEMB + k] * gW1[k * kGH + c];
        M11[r * kGH + c] = s;
    }
}

__global__ void w2t_kernel(const float* __restrict__ W, _Float16* __restrict__ Bt) {
    int i = blockIdx.x * 256 + threadIdx.x;   // 65536
    int k = i >> 8, n = i & 255;
    Bt[(size_t)n * kGH + k] = (_Float16)W[(size_t)k * kGH + n];
}

// ---------------------------------------------------------------------------
// Conv1 fused: h2[v] = relu(dinv[v]*(dinv[v]*M11[x[v]] + sum_s dinv[s]*M11[x[s]]) + b1)
// One wave per node, lane covers 4 channels. 8-wide ILP gathers.
// ---------------------------------------------------------------------------
__global__ void aggregate1_kernel(const int2* __restrict__ xd,
                                  const int* __restrict__ row_ptr, const int* __restrict__ col_idx,
                                  const float* __restrict__ M11, const float* __restrict__ bias,
                                  _Float16* __restrict__ out) {
    int side = blockIdx.y;
    const int2* xdb = xd + (size_t)side * kN;
    const int* rp = row_ptr + side * (kN + 1);
    const int* ci = col_idx + (size_t)side * kE;
    _Float16* ob = out + (size_t)side * kN * kGH;

    int wave = threadIdx.x >> 6;
    int lane = threadIdx.x & 63;
    int v = blockIdx.x * 4 + wave;
    if (v >= kN) return;
    int c = lane * 4;
    float4 bia = *(const float4*)(bias + c);
    int2 xv = xdb[v];
    float dv = __int_as_float(xv.y);
    float4 m = *(const float4*)(M11 + xv.x * kGH + c);
    float4 acc = make_float4(dv * m.x, dv * m.y, dv * m.z, dv * m.w);
    int e0 = rp[v], e1 = rp[v + 1];
    for (int base = e0; base < e1; base += 64) {
        int cnt = min(64, e1 - base);
        int idxl = (base + lane < e1) ? ci[base + lane] : 0;
        int j = 0;
        for (; j + 8 <= cnt; j += 8) {
            int2 xs[8];
            #pragma unroll
            for (int u = 0; u < 8; u++) xs[u] = xdb[__shfl(idxl, j + u)];
            #pragma unroll
            for (int u = 0; u < 8; u++) {
                float ds = __int_as_float(xs[u].y);
                float4 ms = *(const float4*)(M11 + xs[u].x * kGH + c);
                acc.x += ds * ms.x; acc.y += ds * ms.y;
                acc.z += ds * ms.z; acc.w += ds * ms.w;
            }
        }
        for (; j < cnt; j++) {
            int2 xs = xdb[__shfl(idxl, j)];
            float ds = __int_as_float(xs.y);
            float4 ms = *(const float4*)(M11 + xs.x * kGH + c);
            acc.x += ds * ms.x; acc.y += ds * ms.y;
            acc.z += ds * ms.z; acc.w += ds * ms.w;
        }
    }
    half4v o;
    o[0] = (_Float16)fmaxf(dv * acc.x + bia.x, 0.f);
    o[1] = (_Float16)fmaxf(dv * acc.y + bia.y, 0.f);
    o[2] = (_Float16)fmaxf(dv * acc.z + bia.z, 0.f);
    o[3] = (_Float16)fmaxf(dv * acc.w + bia.w, 0.f);
    *(half4v*)(ob + (size_t)v * kGH + c) = o;
}

// ---------------------------------------------------------------------------
// Conv2 GEMM via MFMA f16, LDS-tiled: hs = dinv ⊙ (h2 @ W2)
// BM=128, BN=128, BK=64. 256 threads = 4 waves (2x2); wave = 64x64 = 4x4 MFMA tiles.
// A fp16 [N,256] row-major; Bt fp16 [256,256] n-major. LDS stride padded to 72.
// ---------------------------------------------------------------------------
__launch_bounds__(256)
__global__ void gemm2_mfma_kernel(const _Float16* __restrict__ A,
                                  const _Float16* __restrict__ Bt,
                                  const float* __restrict__ dinv,
                                  _Float16* __restrict__ C) {
    __shared__ _Float16 As[128][72];
    __shared__ _Float16 Bs[128][72];

    int side = blockIdx.z;
    const _Float16* Ab = A + (size_t)side * kN * kGH;
    const float* db = dinv + (size_t)side * kN;
    _Float16* Cb = C + (size_t)side * kN * kGH;

    int tid = threadIdx.x;
    int wave = tid >> 6, lane = tid & 63;
    int quad = lane >> 4, r = lane & 15;
    int wm = wave >> 1, wn = wave & 1;
    int row0 = blockIdx.x * 128;
    int col0 = blockIdx.y * 128;

    floatx4 acc[4][4];
    #pragma unroll
    for (int i = 0; i < 4; i++)
        #pragma unroll
        for (int j = 0; j < 4; j++) acc[i][j] = (floatx4){0.f, 0.f, 0.f, 0.f};

    for (int k0 = 0; k0 < kGH; k0 += 64) {
        // Stage A tile (128x64) and B tile (128x64), coalesced half8 loads.
        #pragma unroll
        for (int u = 0; u < 4; u++) {
            int idx = tid + u * 256;           // 0..1023
            int row = idx >> 3;                // 0..127
            int seg = (idx & 7) * 8;           // 0..56
            int gr = row0 + row;
            if (gr >= kN) gr = kN - 1;
            *(half8v*)&As[row][seg] = *(const half8v*)(Ab + (size_t)gr * kGH + k0 + seg);
            *(half8v*)&Bs[row][seg] = *(const half8v*)(Bt + (size_t)(col0 + row) * kGH + k0 + seg);
        }
        __syncthreads();
        #pragma unroll
        for (int ks = 0; ks < 2; ks++) {
            half8v af[4], bf[4];
            #pragma unroll
            for (int mt = 0; mt < 4; mt++)
                af[mt] = *(const half8v*)&As[wm * 64 + mt * 16 + r][ks * 32 + quad * 8];
            #pragma unroll
            for (int nt = 0; nt < 4; nt++)
                bf[nt] = *(const half8v*)&Bs[wn * 64 + nt * 16 + r][ks * 32 + quad * 8];
            #pragma unroll
            for (int mt = 0; mt < 4; mt++)
                #pragma unroll
                for (int nt = 0; nt < 4; nt++)
                    acc[mt][nt] = __builtin_amdgcn_mfma_f32_16x16x32_f16(af[mt], bf[nt],
                                                                         acc[mt][nt], 0, 0, 0);
        }
        __syncthreads();
    }

    // Epilogue: C/D layout col = r, row = quad*4 + i
    #pragma unroll
    for (int mt = 0; mt < 4; mt++) {
        #pragma unroll
        for (int i = 0; i < 4; i++) {
            int grow = row0 + wm * 64 + mt * 16 + quad * 4 + i;
            if (grow >= kN) continue;
            float rs = db[grow];
            #pragma unroll
            for (int nt = 0; nt < 4; nt++) {
                int gcol = col0 + wn * 64 + nt * 16 + r;
                Cb[(size_t)grow * kGH + gcol] = (_Float16)(acc[mt][nt][i] * rs);
            }
        }
    }
}

// ---------------------------------------------------------------------------
// Conv2 aggregate: h4[v] = relu(dinv[v]*(hs[v] + sum_s hs[s]) + b2)  (hs fp16)
// 8-wide ILP gather version.
// ---------------------------------------------------------------------------
__global__ void aggregate2_kernel(const _Float16* __restrict__ hs, const float* __restrict__ dinv,
                                  const int* __restrict__ row_ptr, const int* __restrict__ col_idx,
                                  const float* __restrict__ bias, _Float16* __restrict__ out) {
    int side = blockIdx.y;
    const _Float16* hb = hs + (size_t)side * kN * kGH;
    const float* dv_ = dinv + side * kN;
    const int* rp = row_ptr + side * (kN + 1);
    const int* ci = col_idx + (size_t)side * kE;
    _Float16* ob = out + (size_t)side * kN * kGH;

    int wave = threadIdx.x >> 6;
    int lane = threadIdx.x & 63;
    int v = blockIdx.x * 4 + wave;
    if (v >= kN) return;
    int c = lane * 4;
    float4 bia = *(const float4*)(bias + c);
    float dv = dv_[v];
    half4v hv = *(const half4v*)(hb + (size_t)v * kGH + c);   // self-loop term
    float a0 = (float)hv[0], a1 = (float)hv[1], a2 = (float)hv[2], a3 = (float)hv[3];
    int e0 = rp[v], e1 = rp[v + 1];
    for (int base = e0; base < e1; base += 64) {
        int cnt = min(64, e1 - base);
        int idxl = (base + lane < e1) ? ci[base + lane] : 0;
        int j = 0;
        for (; j + 8 <= cnt; j += 8) {
            half4v h[8];
            #pragma unroll
            for (int u = 0; u < 8; u++)
                h[u] = *(const half4v*)(hb + (size_t)__shfl(idxl, j + u) * kGH + c);
            #pragma unroll
            for (int u = 0; u < 8; u++) {
                a0 += (float)h[u][0]; a1 += (float)h[u][1];
                a2 += (float)h[u][2]; a3 += (float)h[u][3];
            }
        }
        for (; j < cnt; j++) {
            half4v h = *(const half4v*)(hb + (size_t)__shfl(idxl, j) * kGH + c);
            a0 += (float)h[0]; a1 += (float)h[1]; a2 += (float)h[2]; a3 += (float)h[3];
        }
    }
    half4v o;
    o[0] = (_Float16)fmaxf(dv * a0 + bia.x, 0.f);
    o[1] = (_Float16)fmaxf(dv * a1 + bia.y, 0.f);
    o[2] = (_Float16)fmaxf(dv * a2 + bia.z, 0.f);
    o[3] = (_Float16)fmaxf(dv * a3 + bia.w, 0.f);
    *(half4v*)(ob + (size_t)v * kGH + c) = o;
}

// ---------------------------------------------------------------------------
// Global mean pool (sorted batch -> binary search, atomic-free). fp16 in, fp32 out.
// pooled stacked [2G, GH].
// ---------------------------------------------------------------------------
__global__ void pool_kernel(const _Float16* __restrict__ h,
                            const int* __restrict__ batch1, const int* __restrict__ batch2,
                            float* __restrict__ pooled) {
    int side = blockIdx.y;
    const _Float16* hb = h + (size_t)side * kN * kGH;
    const int* batch = side ? batch2 : batch1;
    int g = blockIdx.x;
    int lo = 0, hi = kN;
    while (lo < hi) { int mid = (lo + hi) >> 1; if (batch[mid] < g) lo = mid + 1; else hi = mid; }
    int start = lo;
    lo = start; hi = kN;
    while (lo < hi) { int mid = (lo + hi) >> 1; if (batch[mid] < g + 1) lo = mid + 1; else hi = mid; }
    int end = lo;
    int c = threadIdx.x;  // 256
    float s = 0.f;
    for (int v = start; v < end; v++) s += (float)hb[(size_t)v * kGH + c];
    float cnt = (float)(end - start);
    pooled[(size_t)(side * kG + g) * kGH + c] = s / fmaxf(cnt, 1.0f);
}

// ---------------------------------------------------------------------------
// Entity embedding gather + relu, both sides stacked [2G, EMB]
// ---------------------------------------------------------------------------
__global__ void ent_gather_kernel(const float* __restrict__ emb,
                                  const int* __restrict__ ent1, const int* __restrict__ ent2,
                                  float* __restrict__ out) {
    int i = blockIdx.x * blockDim.x + threadIdx.x;
    if (i >= 2 * kG * kEMB) return;
    int g = i >> 7, c = i & 127;
    int idx = (g < kG) ? ent1[g] : ent2[g - kG];
    out[i] = fmaxf(emb[(size_t)idx * kEMB + c], 0.f);
}

// ---------------------------------------------------------------------------
// egs = relu(concat(g1,e1) + concat(g2,e2))  with stacked [2G,·] inputs
// ---------------------------------------------------------------------------
__global__ void egs_kernel(const float* __restrict__ gfc, const float* __restrict__ ento,
                           float* __restrict__ egs) {
    int i = blockIdx.x * blockDim.x + threadIdx.x;
    if (i >= kG * kHID) return;
    int g = i >> 9, c = i & 511;
    float v;
    if (c < kGH) v = gfc[(size_t)g * kGH + c] + gfc[(size_t)(g + kG) * kGH + c];
    else         v = ento[(size_t)g * kEH + c - kGH] + ento[(size_t)(g + kG) * kEH + c - kGH];
    egs[i] = fmaxf(v, 0.f);
}

// ---------------------------------------------------------------------------
// Generic tiled fp32 GEMM (tail layers): C = (A@B) [+bias] [relu]
// ---------------------------------------------------------------------------
__launch_bounds__(256)
__global__ void gemm_kernel(const float* __restrict__ A, const float* __restrict__ B,
                            float* __restrict__ C, int M, int N, int K,
                            const float* __restrict__ bias, int relu) {
    __shared__ float As[16][64];
    __shared__ float Bs[16][64];
    int tid = threadIdx.x;
    int tx = tid & 15, ty = tid >> 4;
    int row0 = blockIdx.y * 64, col0 = blockIdx.x * 64;
    float acc[4][4] = {};
    for (int k0 = 0; k0 < K; k0 += 16) {
        {   // A tile 64x16, transposed into LDS
            int r = tid >> 2, seg = tid & 3;
            int gr = row0 + r;
            float4 v = make_float4(0.f, 0.f, 0.f, 0.f);
            if (gr < M) v = *(const float4*)(A + (size_t)gr * K + k0 + seg * 4);
            As[seg * 4 + 0][r] = v.x; As[seg * 4 + 1][r] = v.y;
            As[seg * 4 + 2][r] = v.z; As[seg * 4 + 3][r] = v.w;
        }
        {   // B tile 16x64
            int kr = tid >> 4, c4 = (tid & 15) * 4;
            float4 v = *(const float4*)(B + (size_t)(k0 + kr) * N + col0 + c4);
            *(float4*)&Bs[kr][c4] = v;
        }
        __syncthreads();
        #pragma unroll
        for (int k = 0; k < 16; k++) {
            float a[4], b[4];
            #pragma unroll
            for (int i = 0; i < 4; i++) a[i] = As[k][ty * 4 + i];
            #pragma unroll
            for (int j = 0; j < 4; j++) b[j] = Bs[k][tx * 4 + j];
            #pragma unroll
            for (int i = 0; i < 4; i++)
                #pragma unroll
                for (int j = 0; j < 4; j++)
                    acc[i][j] += a[i] * b[j];
        }
        __syncthreads();
    }
    #pragma unroll
    for (int i = 0; i < 4; i++) {
        int gr = row0 + ty * 4 + i;
        if (gr >= M) continue;
        #pragma unroll
        for (int j = 0; j < 4; j++) {
            int gc = col0 + tx * 4 + j;
            float v = acc[i][j];
            if (bias) v += bias[gc];
            if (relu) v = fmaxf(v, 0.f);
            C[(size_t)gr * N + gc] = v;
        }
    }
}

// ---------------------------------------------------------------------------
// Host launch
// ---------------------------------------------------------------------------
static inline char* carve(char*& p, size_t bytes) {
    char* r = p;
    p += (bytes + 255) & ~(size_t)255;
    return r;
}

extern "C" void kernel_launch(void* const* d_in, const int* in_sizes, int n_in,
                              void* d_out, int out_size, void* d_ws, size_t ws_size,
                              hipStream_t stream) {
    const int*   x1       = (const int*)d_in[0];
    const int*   ei1      = (const int*)d_in[1];
    const int*   ent1     = (const int*)d_in[2];
    const int*   batch1   = (const int*)d_in[3];
    const int*   x2       = (const int*)d_in[4];
    const int*   ei2      = (const int*)d_in[5];
    const int*   ent2     = (const int*)d_in[6];
    const int*   batch2   = (const int*)d_in[7];
    const float* atom_emb = (const float*)d_in[8];
    const float* gW1      = (const float*)d_in[9];
    const float* gb1      = (const float*)d_in[10];
    const float* gW2      = (const float*)d_in[11];
    const float* gb2      = (const float*)d_in[12];
    const float* fcW      = (const float*)d_in[13];
    const float* fcb      = (const float*)d_in[14];
    const float* ent_emb  = (const float*)d_in[15];
    const float* eW1      = (const float*)d_in[16];
    const float* eb1      = (const float*)d_in[17];
    const float* eW2      = (const float*)d_in[18];
    const float* eb2      = (const float*)d_in[19];
    const float* dW1      = (const float*)d_in[20];
    const float* db1      = (const float*)d_in[21];
    const float* dW2      = (const float*)d_in[22];
    const float* db2      = (const float*)d_in[23];
    const float* dW3      = (const float*)d_in[24];
    const float* db3      = (const float*)d_in[25];
    float* out = (float*)d_out;

    // Workspace carve (h4 reuses h2 buffer: h2 is dead after gemm2)
    char* p = (char*)d_ws;
    _Float16* h2_h   = (_Float16*)carve(p, (size_t)2 * kN * kGH * 2);  // also h4
    _Float16* hs_h   = (_Float16*)carve(p, (size_t)2 * kN * kGH * 2);
    int*   col_idx = (int*)  carve(p, (size_t)2 * kE * 4);
    int*   row_ptr = (int*)  carve(p, (size_t)2 * (kN + 1) * 4);
    int*   counts  = (int*)  carve(p, (size_t)2 * kN * 4);
    int*   fillc   = (int*)  carve(p, (size_t)2 * kN * 4);
    float* dinv    = (float*)carve(p, (size_t)2 * kN * 4);
    int2*  xd      = (int2*) carve(p, (size_t)2 * kN * 8);
    int*   bsum    = (int*)  carve(p, (size_t)2 * kNB * 4);
    int*   boff    = (int*)  carve(p, (size_t)2 * kNB * 4);
    float* M11     = (float*)carve(p, 11 * kGH * 4);
    _Float16* w2t  = (_Float16*)carve(p, (size_t)kGH * kGH * 2);
    float* pooled  = (float*)carve(p, (size_t)2 * kG * kGH * 4);   // stacked both sides
    float* gfc     = (float*)carve(p, (size_t)2 * kG * kGH * 4);
    float* e0      = (float*)carve(p, (size_t)2 * kG * kEMB * 4);
    float* etmp    = (float*)carve(p, (size_t)2 * kG * kEH * 4);
    float* ento    = (float*)carve(p, (size_t)2 * kG * kEH * 4);
    float* egs     = (float*)carve(p, (size_t)kG * kHID * 4);
    float* dh1     = (float*)carve(p, (size_t)kG * kHID * 4);
    float* dh2     = (float*)carve(p, (size_t)kG * kHID * 4);

    // Precompute: M11 = atom_emb@gW1; W2^T fp16
    m11_kernel<<<1, 256, 0, stream>>>(atom_emb, gW1, M11);
    w2t_kernel<<<kGH * kGH / 256, 256, 0, stream>>>(gW2, w2t);

    // --- Graph structure, both sides (gridDim.y = 2) ---
    hipMemsetAsync(counts, 0, (size_t)2 * kN * 4, stream);
    hipMemsetAsync(fillc, 0, (size_t)2 * kN * 4, stream);
    deg_kernel<<<dim3(kE / 256, 2), 256, 0, stream>>>(ei1 + kE, ei2 + kE, counts);
    bsum_kernel<<<dim3(kNB, 2), 256, 0, stream>>>(counts, bsum);
    bscan_kernel<<<2, 256, 0, stream>>>(bsum, boff);
    scanf_kernel<<<dim3(kNB, 2), 256, 0, stream>>>(counts, boff, row_ptr, dinv, xd, x1, x2);
    fill_kernel<<<dim3(kE / 256, 2), 256, 0, stream>>>(ei1, ei2, row_ptr, fillc, col_idx);

    // --- Conv1 fused -> fp16 h2 ---
    aggregate1_kernel<<<dim3((kN + 3) / 4, 2), 256, 0, stream>>>(xd, row_ptr, col_idx,
                                                                 M11, gb1, h2_h);
    // --- Conv2 GEMM (MFMA f16, LDS-tiled): hs = dinv ⊙ (h2 @ W2) ---
    gemm2_mfma_kernel<<<dim3((kN + 127) / 128, kGH / 128, 2), 256, 0, stream>>>(h2_h, w2t,
                                                                                dinv, hs_h);
    // --- Conv2 aggregate -> h4 (reuses h2 buffer) ---
    aggregate2_kernel<<<dim3((kN + 3) / 4, 2), 256, 0, stream>>>(hs_h, dinv, row_ptr, col_idx,
                                                                 gb2, h2_h);
    // --- Mean pool -> stacked [2G, GH] fp32 ---
    pool_kernel<<<dim3(kG, 2), 256, 0, stream>>>(h2_h, batch1, batch2, pooled);

    // --- fc on pooled (both sides in one GEMM, no relu) ---
    gemm_kernel<<<dim3(kGH / 64, 2 * kG / 64), 256, 0, stream>>>(pooled, fcW, gfc,
                                                                 2 * kG, kGH, kGH, fcb, 0);

    // --- Entity encoders (both sides stacked) ---
    ent_gather_kernel<<<(2 * kG * kEMB + 255) / 256, 256, 0, stream>>>(ent_emb, ent1, ent2, e0);
    gemm_kernel<<<dim3(kEH / 64, 2 * kG / 64), 256, 0, stream>>>(e0, eW1, etmp,
                                                                 2 * kG, kEH, kEMB, eb1, 1);
    gemm_kernel<<<dim3(kEH / 64, 2 * kG / 64), 256, 0, stream>>>(etmp, eW2, ento,
                                                                 2 * kG, kEH, kEH, eb2, 1);

    // --- Decoder ---
    egs_kernel<<<(kG * kHID + 255) / 256, 256, 0, stream>>>(gfc, ento, egs);
    gemm_kernel<<<dim3(kHID / 64, kG / 64), 256, 0, stream>>>(egs, dW1, dh1,
                                                              kG, kHID, kHID, db1, 1);
    gemm_kernel<<<dim3(kHID / 64, kG / 64), 256, 0, stream>>>(dh1, dW2, dh2,
                                                              kG, kHID, kHID, db2, 1);
    gemm_kernel<<<dim3(kOUT / 64, kG / 64), 256, 0, stream>>>(dh2, dW3, out,
                                                              kG, kOUT, kHID, db3, 0);
}